// Round 1
// baseline (151.326 us; speedup 1.0000x reference)
//
#include <hip/hip_runtime.h>
#include <hip/hip_bf16.h>

#define N 16384
#define TPB 256
#define SPLIT 16          // j-chunks per direction
#define CHUNK (N / SPLIT) // 1024 ref points per block

typedef float v2f __attribute__((ext_vector_type(2)));

// ---- init: minbuf[0 .. 2N) = +inf (as int bit pattern) ----
__global__ void init_kernel(int* __restrict__ minbuf) {
    int idx = blockIdx.x * blockDim.x + threadIdx.x;
    if (idx < 2 * N) minbuf[idx] = 0x7F800000; // +inf
}

// ---- main: per-thread min over a chunk of reference points ----
// grid: 2 * SPLIT * (N/TPB) blocks. dir = b&1, jc = (b>>1)&(SPLIT-1), itile = b>>1>>log2(SPLIT)
__global__ void __launch_bounds__(TPB) chamfer_kernel(const float* __restrict__ P,
                                                      const float* __restrict__ Q,
                                                      int* __restrict__ minbuf) {
    int b    = blockIdx.x;
    int dir  = b & 1;
    int rest = b >> 1;
    int jc   = rest & (SPLIT - 1);
    int it   = rest / SPLIT;

    const float* __restrict__ qp = dir ? Q : P; // queries
    const float* __restrict__ rp = dir ? P : Q; // references

    int i = it * TPB + (int)threadIdx.x;
    float qx = qp[3 * i + 0];
    float qy = qp[3 * i + 1];
    float qz = qp[3 * i + 2];
    v2f qxv = {qx, qx}, qyv = {qy, qy}, qzv = {qz, qz};

    v2f vmin = {__builtin_inff(), __builtin_inff()};

    int j0 = jc * CHUNK;
#pragma unroll 8
    for (int j = j0; j < j0 + CHUNK; j += 2) {
        // two reference points; j is wave-uniform -> scalar loads
        v2f px = {rp[3 * j + 0], rp[3 * j + 3]};
        v2f py = {rp[3 * j + 1], rp[3 * j + 4]};
        v2f pz = {rp[3 * j + 2], rp[3 * j + 5]};
        v2f dx = qxv - px;
        v2f dy = qyv - py;
        v2f dz = qzv - pz;
        v2f d  = dx * dx;
        d = __builtin_elementwise_fma(dy, dy, d);
        d = __builtin_elementwise_fma(dz, dz, d);
        vmin = __builtin_elementwise_min(vmin, d);
    }
    float m = fminf(vmin.x, vmin.y);

    // non-negative floats: int compare == float compare
    atomicMin(&minbuf[dir * N + i], __float_as_int(m));
}

// ---- reduce: mean(min dir0) + mean(min dir1) = sum(all)/N ----
__global__ void reduce_kernel(const int* __restrict__ minbuf, float* __restrict__ out) {
    float s = 0.0f;
    for (int idx = threadIdx.x; idx < 2 * N; idx += blockDim.x)
        s += __int_as_float(minbuf[idx]);
    // wave-64 reduce
    for (int off = 32; off > 0; off >>= 1) s += __shfl_down(s, off, 64);
    __shared__ float partial[TPB / 64];
    int lane = threadIdx.x & 63;
    int wid  = threadIdx.x >> 6;
    if (lane == 0) partial[wid] = s;
    __syncthreads();
    if (threadIdx.x == 0) {
        float t = 0.0f;
        for (int w = 0; w < TPB / 64; ++w) t += partial[w];
        out[0] = t / (float)N;
    }
}

extern "C" void kernel_launch(void* const* d_in, const int* in_sizes, int n_in,
                              void* d_out, int out_size, void* d_ws, size_t ws_size,
                              hipStream_t stream) {
    const float* p_hat = (const float*)d_in[0];
    const float* p     = (const float*)d_in[1];
    int*   minbuf = (int*)d_ws;
    float* out    = (float*)d_out;

    init_kernel<<<(2 * N + TPB - 1) / TPB, TPB, 0, stream>>>(minbuf);
    chamfer_kernel<<<2 * SPLIT * (N / TPB), TPB, 0, stream>>>(p_hat, p, minbuf);
    reduce_kernel<<<1, TPB, 0, stream>>>(minbuf, out);
}

// Round 2
// 113.062 us; speedup vs baseline: 1.3384x; 1.3384x over previous
//
#include <hip/hip_runtime.h>
#include <hip/hip_bf16.h>

#define N 16384
#define TPB 256
#define SPLIT 32           // ref-chunks per direction
#define CHUNK (N / SPLIT)  // 512 refs per block
#define QPT 2              // queries per thread
#define QTILE (TPB * QPT)  // 512 queries per block
#define INF_BITS 0x7F800000

// ws layout: [0, 2N) float4 packed points {x,y,z,|r|^2}; then [2N) ints minbuf
// ---- pack: build {x,y,z,|r|^2} for both clouds + init minbuf to +inf ----
__global__ void pack_kernel(const float* __restrict__ p_hat,
                            const float* __restrict__ p,
                            float4* __restrict__ q4,
                            int* __restrict__ minbuf) {
    int idx = blockIdx.x * blockDim.x + threadIdx.x;
    if (idx >= 2 * N) return;
    const float* src = (idx < N) ? p_hat : p;
    int k = (idx < N) ? idx : idx - N;
    float x = src[3 * k + 0], y = src[3 * k + 1], z = src[3 * k + 2];
    q4[idx] = make_float4(x, y, z, x * x + y * y + z * z);
    minbuf[idx] = INF_BITS;
}

// ---- main: 4 VALU ops per pair: 3 fma + 1 min ----
// grid: 2 dirs x SPLIT x (N/QTILE). b layout: dir | jc | qtile
__global__ void __launch_bounds__(TPB) chamfer_kernel(const float4* __restrict__ q4,
                                                      int* __restrict__ minbuf) {
    int b    = blockIdx.x;
    int dir  = b & 1;
    int rest = b >> 1;
    int jc   = rest & (SPLIT - 1);
    int qt   = rest / SPLIT;

    // dir 0: queries = p_hat half [0,N), refs = p half [N,2N). dir 1: swapped.
    const float4* __restrict__ qp = q4 + (dir ? N : 0);
    const float4* __restrict__ rp = q4 + (dir ? 0 : N);

    int i0 = qt * QTILE + (int)threadIdx.x;
    int i1 = i0 + TPB;
    float4 q0 = qp[i0];
    float4 q1 = qp[i1];
    float m2x0 = -2.0f * q0.x, m2y0 = -2.0f * q0.y, m2z0 = -2.0f * q0.z;
    float m2x1 = -2.0f * q1.x, m2y1 = -2.0f * q1.y, m2z1 = -2.0f * q1.z;

    float vmin0 = __builtin_inff();
    float vmin1 = __builtin_inff();

    int j0 = jc * CHUNK;
#pragma unroll 8
    for (int j = j0; j < j0 + CHUNK; ++j) {
        float4 r = rp[j];  // wave-uniform -> s_load_dwordx4
        float t0 = __builtin_fmaf(r.x, m2x0,
                   __builtin_fmaf(r.y, m2y0,
                   __builtin_fmaf(r.z, m2z0, r.w)));
        vmin0 = fminf(vmin0, t0);
        float t1 = __builtin_fmaf(r.x, m2x1,
                   __builtin_fmaf(r.y, m2y1,
                   __builtin_fmaf(r.z, m2z1, r.w)));
        vmin1 = fminf(vmin1, t1);
    }
    // d^2 = |q|^2 + (|r|^2 - 2 q.r); clamp to 0 (monotone, commutes with min)
    float m0 = fmaxf(vmin0 + q0.w, 0.0f);
    float m1 = fmaxf(vmin1 + q1.w, 0.0f);
    atomicMin(&minbuf[dir * N + i0], __float_as_int(m0));
    atomicMin(&minbuf[dir * N + i1], __float_as_int(m1));
}

// ---- reduce: out = sum(all 2N mins) / N ----
__global__ void __launch_bounds__(1024) reduce_kernel(const int* __restrict__ minbuf,
                                                      float* __restrict__ out) {
    const int4* mb4 = (const int4*)minbuf;  // 2N/4 = 8192 int4
    float s = 0.0f;
#pragma unroll
    for (int k = 0; k < (2 * N / 4) / 1024; ++k) {
        int4 v = mb4[k * 1024 + threadIdx.x];
        s += __int_as_float(v.x) + __int_as_float(v.y) +
             __int_as_float(v.z) + __int_as_float(v.w);
    }
    for (int off = 32; off > 0; off >>= 1) s += __shfl_down(s, off, 64);
    __shared__ float partial[1024 / 64];
    int lane = threadIdx.x & 63;
    int wid  = threadIdx.x >> 6;
    if (lane == 0) partial[wid] = s;
    __syncthreads();
    if (threadIdx.x == 0) {
        float t = 0.0f;
        for (int w = 0; w < 1024 / 64; ++w) t += partial[w];
        out[0] = t / (float)N;
    }
}

extern "C" void kernel_launch(void* const* d_in, const int* in_sizes, int n_in,
                              void* d_out, int out_size, void* d_ws, size_t ws_size,
                              hipStream_t stream) {
    const float* p_hat = (const float*)d_in[0];
    const float* p     = (const float*)d_in[1];
    float4* q4    = (float4*)d_ws;
    int*    minbuf = (int*)((char*)d_ws + 2 * N * sizeof(float4));
    float*  out   = (float*)d_out;

    pack_kernel<<<(2 * N + TPB - 1) / TPB, TPB, 0, stream>>>(p_hat, p, q4, minbuf);
    chamfer_kernel<<<2 * SPLIT * (N / QTILE), TPB, 0, stream>>>(q4, minbuf);
    reduce_kernel<<<1, 1024, 0, stream>>>(minbuf, out);
}